// Round 2
// baseline (3309.332 us; speedup 1.0000x reference)
//
#include <hip/hip_runtime.h>

#define BN 262144

typedef short bf16x8 __attribute__((ext_vector_type(8)));
typedef float f32x4 __attribute__((ext_vector_type(4)));
typedef float f32x16 __attribute__((ext_vector_type(16)));

#define MFMA16(a,b,c) __builtin_amdgcn_mfma_f32_16x16x32_bf16((a),(b),(c),0,0,0)
#define MFMA32(a,b,c) __builtin_amdgcn_mfma_f32_32x32x16_bf16((a),(b),(c),0,0,0)

__device__ __forceinline__ unsigned short f2bf(float f) {
  union { float f; unsigned int u; } x; x.f = f;
  unsigned int u = x.u + 0x7fffu + ((x.u >> 16) & 1u);
  return (unsigned short)(u >> 16);
}
__device__ __forceinline__ float bf2f(unsigned int h) {
  union { unsigned int u; float f; } x; x.u = h << 16;
  return x.f;
}

// ws frag arrays (ushort units).
// Wide (32x32x16):  elem ((nt*KS+s)*64+lane)*8+j : n=nt*32+(lane&31), k=s*16+(lane>>5)*8+j
// Narrow (16x16x32): elem ((nt*KS+s)*64+lane)*8+j : n=nt*16+(lane&15), k=s*32+(lane>>4)*8+j
#define O_Q1 0        // wide  W1^T: B[k][n]=W1[n*64+k]   K=64  N=256 KS=4
#define O_Q2 16384    // wide  W2^T: B[k][n]=W2[n*256+k]  K=256 N=256 KS=16
#define O_Q4 81920    // wide  W3  : B[k][n]=W3[k*256+n]  K=64  N=256 KS=4
#define O_Q5 98304    // wide  W2  : B[k][n]=W2[k*256+n]  K=256 N=256 KS=16
#define O_Q3 163840   // narr  W3^T: B[k][n]=W3[n*256+k]  K=256 N=64  KS=8
#define O_Q6 180224   // narr  W1  : B[k][n]=W1[k*64+n]   K=256 N=64  KS=8
#define N_WS 196608

__global__ void invres_prep(const float* __restrict__ W1, const float* __restrict__ W2,
                            const float* __restrict__ W3, unsigned short* __restrict__ wsb) {
  int idx = blockIdx.x * 256 + threadIdx.x;
  if (idx >= N_WS) return;
  int j = idx & 7;
  int lane = (idx >> 3) & 63;
  int nw = lane & 31, kw = (lane >> 5) * 8 + j;   // wide pieces
  int nn = lane & 15, kn = (lane >> 4) * 8 + j;   // narrow pieces
  float val;
  if (idx < O_Q2) {                // Q1 wide KS=4
    int g = idx >> 9; int s = g & 3; int nt = g >> 2;
    val = W1[(nt * 32 + nw) * 64 + (s * 16 + kw)];
  } else if (idx < O_Q4) {         // Q2 wide KS=16
    int g = (idx - O_Q2) >> 9; int s = g & 15; int nt = g >> 4;
    val = W2[(nt * 32 + nw) * 256 + (s * 16 + kw)];
  } else if (idx < O_Q5) {         // Q4 wide KS=4
    int g = (idx - O_Q4) >> 9; int s = g & 3; int nt = g >> 2;
    val = W3[(s * 16 + kw) * 256 + (nt * 32 + nw)];
  } else if (idx < O_Q3) {         // Q5 wide KS=16
    int g = (idx - O_Q5) >> 9; int s = g & 15; int nt = g >> 4;
    val = W2[(s * 16 + kw) * 256 + (nt * 32 + nw)];
  } else if (idx < O_Q6) {         // Q3 narrow KS=8
    int g = (idx - O_Q3) >> 9; int s = g & 7; int nt = g >> 3;
    val = W3[(nt * 16 + nn) * 256 + (s * 32 + kn)];
  } else {                         // Q6 narrow KS=8
    int g = (idx - O_Q6) >> 9; int s = g & 7; int nt = g >> 3;
    val = W1[(s * 32 + kn) * 64 + (nt * 16 + nn)];
  }
  wsb[idx] = f2bf(val);
}

// LDS: bufA 64x256 bf16 (stride 512B, swz) | bufB same | wbuf 64x64 bf16 (stride 128B, swz) | ldp f32[64][4]
#define L_BUFB 32768
#define L_WBUF 65536
#define L_LDP  73728
#define L_SIZE 74752

__global__ void __launch_bounds__(512, 4)
invres_main(const float* __restrict__ y, const float* __restrict__ ldj,
            const float* __restrict__ v, const float* __restrict__ b1,
            const float* __restrict__ b2, const float* __restrict__ b3,
            const unsigned short* __restrict__ wsb, float* __restrict__ out) {
  extern __shared__ char smem[];
  char* bufA = smem;
  char* bufB = smem + L_BUFB;
  char* wbuf = smem + L_WBUF;
  float* ldp = (float*)(smem + L_LDP);

  const int tid = threadIdx.x;
  const int lane = tid & 63;
  const int wid = tid >> 6;
  const int l31 = lane & 31, h32 = lane >> 5;
  const int l15 = lane & 15, g16 = lane >> 4;
  const int ns = wid;        // wide col-slice (32 cols)
  const int nt = wid & 3;    // narrow col-tile (16 cols)
  const int mh = wid >> 2;   // narrow row-half
  const int r0 = blockIdx.x * 64;

  const bf16x8* Q1 = (const bf16x8*)(wsb + O_Q1);
  const bf16x8* Q2 = (const bf16x8*)(wsb + O_Q2);
  const bf16x8* Q3 = (const bf16x8*)(wsb + O_Q3);
  const bf16x8* Q4 = (const bf16x8*)(wsb + O_Q4);
  const bf16x8* Q5 = (const bf16x8*)(wsb + O_Q5);
  const bf16x8* Q6 = (const bf16x8*)(wsb + O_Q6);

  auto wideA = [&](const char* buf, int m, int s) -> bf16x8 {
    int row = m * 32 + l31;
    unsigned byte = ((unsigned)(s * 32 + h32 * 16)) ^ ((unsigned)(row & 7) << 4);
    return *(const bf16x8*)(buf + row * 512 + byte);
  };
  auto storeWide = [&](char* buf, int m, int r, float val) {
    int row = m * 32 + (r & 3) + ((r >> 2) << 3) + h32 * 4;
    int col = ns * 32 + l31;
    *(unsigned short*)(buf + row * 512 + (((unsigned)(col * 2)) ^ ((unsigned)(row & 7) << 4))) = f2bf(val);
  };
  auto narrA = [&](const char* buf, int m, int s) -> bf16x8 {
    int row = (mh * 2 + m) * 16 + l15;
    unsigned byte = ((unsigned)(s * 64 + g16 * 16)) ^ ((unsigned)(row & 7) << 4);
    return *(const bf16x8*)(buf + row * 512 + byte);
  };

  const float bb1 = b1[ns * 32 + l31];
  const float bb2 = b2[ns * 32 + l31];
  const float bb3 = b3[nt * 16 + l15];

  unsigned d1p[16], d2p[16], d0p[4], v0p[4];
  float ldacc[8];
#pragma unroll
  for (int i = 0; i < 8; i++) ldacc[i] = 0.f;

  // ---------------- G1: a1 = elu(y) @ W1^T + b1 ----------------
  {
    f32x16 acc0 = {}, acc1 = {};
#pragma unroll
    for (int s = 0; s < 4; s++) {
      bf16x8 a0, a1;
#pragma unroll
      for (int m = 0; m < 2; m++) {
        const float* yp = y + (size_t)(r0 + m * 32 + l31) * 64 + s * 16 + h32 * 8;
        float4 p = *(const float4*)yp;
        float4 q = *(const float4*)(yp + 4);
        float xv[8] = {p.x, p.y, p.z, p.w, q.x, q.y, q.z, q.w};
        bf16x8 f;
#pragma unroll
        for (int i = 0; i < 8; i++) { float x = xv[i]; x = x > 0.f ? x : (__expf(x) - 1.f); f[i] = (short)f2bf(x); }
        if (m == 0) a0 = f; else a1 = f;
      }
      bf16x8 B = Q1[(ns * 4 + s) * 64 + lane];
      acc0 = MFMA32(a0, B, acc0);
      acc1 = MFMA32(a1, B, acc1);
    }
#pragma unroll
    for (int m = 0; m < 2; m++)
#pragma unroll
      for (int r = 0; r < 16; r++) {
        float a = (m == 0 ? acc0[r] : acc1[r]) + bb1;
        float e = __expf(a);
        float h = a > 0.f ? a : (e - 1.f);
        unsigned dd = f2bf(a > 0.f ? 1.f : e);
        storeWide(bufA, m, r, h);
        int idx = m * 8 + (r >> 1);
        d1p[idx] = (r & 1) ? (d1p[idx] | (dd << 16)) : dd;
      }
  }
  __syncthreads();

  // ---------------- G2: a2 = h1 @ W2^T + b2 ----------------
  {
    f32x16 acc0 = {}, acc1 = {};
#pragma unroll
    for (int s = 0; s < 16; s++) {
      bf16x8 a0 = wideA(bufA, 0, s);
      bf16x8 a1 = wideA(bufA, 1, s);
      bf16x8 B = Q2[(ns * 16 + s) * 64 + lane];
      acc0 = MFMA32(a0, B, acc0);
      acc1 = MFMA32(a1, B, acc1);
    }
#pragma unroll
    for (int m = 0; m < 2; m++)
#pragma unroll
      for (int r = 0; r < 16; r++) {
        float a = (m == 0 ? acc0[r] : acc1[r]) + bb2;
        float e = __expf(a);
        float h = a > 0.f ? a : (e - 1.f);
        unsigned dd = f2bf(a > 0.f ? 1.f : e);
        storeWide(bufB, m, r, h);
        int idx = m * 8 + (r >> 1);
        d2p[idx] = (r & 1) ? (d2p[idx] | (dd << 16)) : dd;
      }
  }
  __syncthreads();

  // ---------------- G3: z = y + h2 @ W3^T + b3 ; d0, v0 ----------------
  {
    f32x4 acc[2] = {};
#pragma unroll
    for (int s = 0; s < 8; s++) {
      bf16x8 B = Q3[(nt * 8 + s) * 64 + lane];
#pragma unroll
      for (int m = 0; m < 2; m++)
        acc[m] = MFMA16(narrA(bufB, m, s), B, acc[m]);
    }
#pragma unroll
    for (int m = 0; m < 2; m++)
#pragma unroll
      for (int r = 0; r < 4; r++) {
        int row = r0 + (mh * 2 + m) * 16 + g16 * 4 + r;
        int col = nt * 16 + l15;
        size_t off = (size_t)row * 64 + col;
        float yv = y[off];
        __builtin_nontemporal_store(yv + acc[m][r] + bb3, out + off);
        unsigned dd = f2bf(yv > 0.f ? 1.f : __expf(yv));
        unsigned vv = f2bf(v[off]);
        int idx = m * 2 + (r >> 1);
        d0p[idx] = (r & 1) ? (d0p[idx] | (dd << 16)) : dd;
        v0p[idx] = (r & 1) ? (v0p[idx] | (vv << 16)) : vv;
      }
  }

  // ---------------- G4 (k=1): u2 = (v0 @ W3) * d2 ----------------
  {
    f32x16 acc0 = {}, acc1 = {};
#pragma unroll
    for (int s = 0; s < 4; s++) {
      bf16x8 a0, a1;
#pragma unroll
      for (int m = 0; m < 2; m++) {
        const float* vp = v + (size_t)(r0 + m * 32 + l31) * 64 + s * 16 + h32 * 8;
        float4 p = *(const float4*)vp;
        float4 q = *(const float4*)(vp + 4);
        float xv[8] = {p.x, p.y, p.z, p.w, q.x, q.y, q.z, q.w};
        bf16x8 f;
#pragma unroll
        for (int i = 0; i < 8; i++) f[i] = (short)f2bf(xv[i]);
        if (m == 0) a0 = f; else a1 = f;
      }
      bf16x8 B = Q4[(ns * 4 + s) * 64 + lane];
      acc0 = MFMA32(a0, B, acc0);
      acc1 = MFMA32(a1, B, acc1);
    }
#pragma unroll
    for (int m = 0; m < 2; m++)
#pragma unroll
      for (int r = 0; r < 16; r++) {
        float u = (m == 0 ? acc0[r] : acc1[r]) * bf2f((d2p[m * 8 + (r >> 1)] >> ((r & 1) * 16)) & 0xffffu);
        storeWide(bufA, m, r, u);
      }
  }
  __syncthreads();

  // ---------------- backward iterations ----------------
  for (int k = 1; k <= 8; ++k) {
    // G5: u1 = (u2 @ W2) * d1
    {
      f32x16 acc0 = {}, acc1 = {};
#pragma unroll
      for (int s = 0; s < 16; s++) {
        bf16x8 a0 = wideA(bufA, 0, s);
        bf16x8 a1 = wideA(bufA, 1, s);
        bf16x8 B = Q5[(ns * 16 + s) * 64 + lane];
        acc0 = MFMA32(a0, B, acc0);
        acc1 = MFMA32(a1, B, acc1);
      }
#pragma unroll
      for (int m = 0; m < 2; m++)
#pragma unroll
        for (int r = 0; r < 16; r++) {
          float u = (m == 0 ? acc0[r] : acc1[r]) * bf2f((d1p[m * 8 + (r >> 1)] >> ((r & 1) * 16)) & 0xffffu);
          storeWide(bufB, m, r, u);
        }
    }
    __syncthreads();

    // G6: w' = (u1 @ W1) * d0 ; log-det ; w' -> wbuf
    {
      float coef = (k & 1) ? (1.f / (float)k) : (-1.f / (float)k);
      f32x4 acc[2] = {};
#pragma unroll
      for (int s = 0; s < 8; s++) {
        bf16x8 B = Q6[(nt * 8 + s) * 64 + lane];
#pragma unroll
        for (int m = 0; m < 2; m++)
          acc[m] = MFMA16(narrA(bufB, m, s), B, acc[m]);
      }
#pragma unroll
      for (int m = 0; m < 2; m++)
#pragma unroll
        for (int r = 0; r < 4; r++) {
          float wv = acc[m][r] * bf2f((d0p[m * 2 + (r >> 1)] >> ((r & 1) * 16)) & 0xffffu);
          ldacc[m * 4 + r] += coef * wv * bf2f((v0p[m * 2 + (r >> 1)] >> ((r & 1) * 16)) & 0xffffu);
          if (k < 8) {
            int row = (mh * 2 + m) * 16 + g16 * 4 + r;
            int col = nt * 16 + l15;
            *(unsigned short*)(wbuf + row * 128 + (((unsigned)(col * 2)) ^ ((unsigned)(row & 7) << 4))) = f2bf(wv);
          }
        }
    }
    if (k < 8) {
      __syncthreads();
      // G4': u2 = (w' @ W3) * d2
      f32x16 acc0 = {}, acc1 = {};
#pragma unroll
      for (int s = 0; s < 4; s++) {
        bf16x8 a0, a1;
#pragma unroll
        for (int m = 0; m < 2; m++) {
          int row = m * 32 + l31;
          unsigned byte = ((unsigned)(s * 32 + h32 * 16)) ^ ((unsigned)(row & 7) << 4);
          bf16x8 a = *(const bf16x8*)(wbuf + row * 128 + byte);
          if (m == 0) a0 = a; else a1 = a;
        }
        bf16x8 B = Q4[(ns * 4 + s) * 64 + lane];
        acc0 = MFMA32(a0, B, acc0);
        acc1 = MFMA32(a1, B, acc1);
      }
#pragma unroll
      for (int m = 0; m < 2; m++)
#pragma unroll
        for (int r = 0; r < 16; r++) {
          float u = (m == 0 ? acc0[r] : acc1[r]) * bf2f((d2p[m * 8 + (r >> 1)] >> ((r & 1) * 16)) & 0xffffu);
          storeWide(bufA, m, r, u);
        }
      __syncthreads();
    }
  }

  // ---------------- log-det epilogue ----------------
#pragma unroll
  for (int i = 0; i < 8; i++) {
    float s = ldacc[i];
    s += __shfl_xor(s, 1);
    s += __shfl_xor(s, 2);
    s += __shfl_xor(s, 4);
    s += __shfl_xor(s, 8);
    ldacc[i] = s;
  }
  if (l15 == 0) {
#pragma unroll
    for (int m = 0; m < 2; m++)
#pragma unroll
      for (int r = 0; r < 4; r++) {
        int row = (mh * 2 + m) * 16 + g16 * 4 + r;
        ldp[row * 4 + nt] = ldacc[m * 4 + r];
      }
  }
  __syncthreads();
  if (tid < 64) {
    float s = ldp[tid * 4] + ldp[tid * 4 + 1] + ldp[tid * 4 + 2] + ldp[tid * 4 + 3];
    int gb = r0 + tid;
    __builtin_nontemporal_store(ldj[gb] + s, out + (size_t)BN * 64 + gb);
  }
}

extern "C" void kernel_launch(void* const* d_in, const int* in_sizes, int n_in,
                              void* d_out, int out_size, void* d_ws, size_t ws_size,
                              hipStream_t stream) {
  const float* y   = (const float*)d_in[0];
  const float* ldj = (const float*)d_in[1];
  const float* v   = (const float*)d_in[2];
  const float* W1  = (const float*)d_in[3];
  const float* b1  = (const float*)d_in[4];
  const float* W2  = (const float*)d_in[5];
  const float* b2  = (const float*)d_in[6];
  const float* W3  = (const float*)d_in[7];
  const float* b3  = (const float*)d_in[8];
  unsigned short* wsb = (unsigned short*)d_ws;
  float* out = (float*)d_out;

  (void)hipFuncSetAttribute(reinterpret_cast<const void*>(&invres_main),
                            hipFuncAttributeMaxDynamicSharedMemorySize, L_SIZE);

  invres_prep<<<N_WS / 256, 256, 0, stream>>>(W1, W2, W3, wsb);
  invres_main<<<BN / 64, 512, L_SIZE, stream>>>(y, ldj, v, b1, b2, b3, wsb, out);
}

// Round 4
// 1586.025 us; speedup vs baseline: 2.0866x; 2.0866x over previous
//
#include <hip/hip_runtime.h>

#define BN 262144

typedef short bf16x8 __attribute__((ext_vector_type(8)));
typedef float f32x4 __attribute__((ext_vector_type(4)));
typedef float f32x16 __attribute__((ext_vector_type(16)));

#define MFMA16(a,b,c) __builtin_amdgcn_mfma_f32_16x16x32_bf16((a),(b),(c),0,0,0)
#define MFMA32(a,b,c) __builtin_amdgcn_mfma_f32_32x32x16_bf16((a),(b),(c),0,0,0)

__device__ __forceinline__ unsigned short f2bf(float f) {
  union { float f; unsigned int u; } x; x.f = f;
  unsigned int u = x.u + 0x7fffu + ((x.u >> 16) & 1u);
  return (unsigned short)(u >> 16);
}
__device__ __forceinline__ float bf2f(unsigned int h) {
  union { unsigned int u; float f; } x; x.u = h << 16;
  return x.f;
}

// ws frag arrays (ushort units).
// Wide (32x32x16):  elem ((nt*KS+s)*64+lane)*8+j : n=nt*32+(lane&31), k=s*16+(lane>>5)*8+j
// Narrow (16x16x32): elem ((nt*KS+s)*64+lane)*8+j : n=nt*16+(lane&15), k=s*32+(lane>>4)*8+j
#define O_Q1 0        // wide  W1^T: B[k][n]=W1[n*64+k]   K=64  N=256 KS=4
#define O_Q2 16384    // wide  W2^T: B[k][n]=W2[n*256+k]  K=256 N=256 KS=16
#define O_Q4 81920    // wide  W3  : B[k][n]=W3[k*256+n]  K=64  N=256 KS=4
#define O_Q5 98304    // wide  W2  : B[k][n]=W2[k*256+n]  K=256 N=256 KS=16
#define O_Q3 163840   // narr  W3^T: B[k][n]=W3[n*256+k]  K=256 N=64  KS=8
#define O_Q6 180224   // narr  W1  : B[k][n]=W1[k*64+n]   K=256 N=64  KS=8
#define N_WS 196608

__global__ void invres_prep(const float* __restrict__ W1, const float* __restrict__ W2,
                            const float* __restrict__ W3, unsigned short* __restrict__ wsb) {
  int idx = blockIdx.x * 256 + threadIdx.x;
  if (idx >= N_WS) return;
  int j = idx & 7;
  int lane = (idx >> 3) & 63;
  int nw = lane & 31, kw = (lane >> 5) * 8 + j;   // wide pieces
  int nn = lane & 15, kn = (lane >> 4) * 8 + j;   // narrow pieces
  float val;
  if (idx < O_Q2) {                // Q1 wide KS=4
    int g = idx >> 9; int s = g & 3; int nt = g >> 2;
    val = W1[(nt * 32 + nw) * 64 + (s * 16 + kw)];
  } else if (idx < O_Q4) {         // Q2 wide KS=16
    int g = (idx - O_Q2) >> 9; int s = g & 15; int nt = g >> 4;
    val = W2[(nt * 32 + nw) * 256 + (s * 16 + kw)];
  } else if (idx < O_Q5) {         // Q4 wide KS=4
    int g = (idx - O_Q4) >> 9; int s = g & 3; int nt = g >> 2;
    val = W3[(s * 16 + kw) * 256 + (nt * 32 + nw)];
  } else if (idx < O_Q3) {         // Q5 wide KS=16
    int g = (idx - O_Q5) >> 9; int s = g & 15; int nt = g >> 4;
    val = W2[(s * 16 + kw) * 256 + (nt * 32 + nw)];
  } else if (idx < O_Q6) {         // Q3 narrow KS=8
    int g = (idx - O_Q3) >> 9; int s = g & 7; int nt = g >> 3;
    val = W3[(nt * 16 + nn) * 256 + (s * 32 + kn)];
  } else {                         // Q6 narrow KS=8
    int g = (idx - O_Q6) >> 9; int s = g & 7; int nt = g >> 3;
    val = W1[(s * 32 + kn) * 64 + (nt * 16 + nn)];
  }
  wsb[idx] = f2bf(val);
}

// LDS: bufA 64x256 bf16 (stride 512B, swz) | bufB same | wbuf 64x64 bf16 (stride 128B, swz) | ldp f32[64][4]
#define L_BUFB 32768
#define L_WBUF 65536
#define L_LDP  73728
#define L_SIZE 74752

__global__ void __launch_bounds__(512, 2)
invres_main(const float* __restrict__ y, const float* __restrict__ ldj,
            const float* __restrict__ v, const float* __restrict__ b1,
            const float* __restrict__ b2, const float* __restrict__ b3,
            const unsigned short* __restrict__ wsb, float* __restrict__ out) {
  extern __shared__ char smem[];
  char* bufA = smem;
  char* bufB = smem + L_BUFB;
  char* wbuf = smem + L_WBUF;
  float* ldp = (float*)(smem + L_LDP);

  const int tid = threadIdx.x;
  const int lane = tid & 63;
  const int wid = tid >> 6;
  const int l31 = lane & 31, h32 = lane >> 5;
  const int l15 = lane & 15, g16 = lane >> 4;
  const int ns = wid;        // wide col-slice (32 cols)
  const int nt = wid & 3;    // narrow col-tile (16 cols)
  const int mh = wid >> 2;   // narrow row-half
  const int r0 = blockIdx.x * 64;

  const bf16x8* Q1 = (const bf16x8*)(wsb + O_Q1);
  const bf16x8* Q2 = (const bf16x8*)(wsb + O_Q2);
  const bf16x8* Q3 = (const bf16x8*)(wsb + O_Q3);
  const bf16x8* Q4 = (const bf16x8*)(wsb + O_Q4);
  const bf16x8* Q5 = (const bf16x8*)(wsb + O_Q5);
  const bf16x8* Q6 = (const bf16x8*)(wsb + O_Q6);

  auto wideA = [&](const char* buf, int m, int s) -> bf16x8 {
    int row = m * 32 + l31;
    unsigned byte = ((unsigned)(s * 32 + h32 * 16)) ^ ((unsigned)(row & 7) << 4);
    return *(const bf16x8*)(buf + row * 512 + byte);
  };
  auto storeWide = [&](char* buf, int m, int r, float val) {
    int row = m * 32 + (r & 3) + ((r >> 2) << 3) + h32 * 4;
    int col = ns * 32 + l31;
    *(unsigned short*)(buf + row * 512 + (((unsigned)(col * 2)) ^ ((unsigned)(row & 7) << 4))) = f2bf(val);
  };
  auto narrA = [&](const char* buf, int m, int s) -> bf16x8 {
    int row = (mh * 2 + m) * 16 + l15;
    unsigned byte = ((unsigned)(s * 64 + g16 * 16)) ^ ((unsigned)(row & 7) << 4);
    return *(const bf16x8*)(buf + row * 512 + byte);
  };

  const float bb1 = b1[ns * 32 + l31];
  const float bb2 = b2[ns * 32 + l31];
  const float bb3 = b3[nt * 16 + l15];

  unsigned d1p[16], d2p[16], d0p[4], v0p[4];
  float ldacc[8];
#pragma unroll
  for (int i = 0; i < 8; i++) ldacc[i] = 0.f;

  // ---------------- G1: a1 = elu(y) @ W1^T + b1 ----------------
  {
    f32x16 acc0 = {}, acc1 = {};
#pragma unroll
    for (int s = 0; s < 4; s++) {
      bf16x8 a0, a1;
#pragma unroll
      for (int m = 0; m < 2; m++) {
        const float* yp = y + (size_t)(r0 + m * 32 + l31) * 64 + s * 16 + h32 * 8;
        f32x4 p = __builtin_nontemporal_load((const f32x4*)yp);
        f32x4 q = __builtin_nontemporal_load((const f32x4*)(yp + 4));
        float xv[8] = {p[0], p[1], p[2], p[3], q[0], q[1], q[2], q[3]};
        bf16x8 f;
#pragma unroll
        for (int i = 0; i < 8; i++) { float x = xv[i]; x = x > 0.f ? x : (__expf(x) - 1.f); f[i] = (short)f2bf(x); }
        if (m == 0) a0 = f; else a1 = f;
      }
      bf16x8 B = Q1[(ns * 4 + s) * 64 + lane];
      acc0 = MFMA32(a0, B, acc0);
      acc1 = MFMA32(a1, B, acc1);
    }
#pragma unroll
    for (int m = 0; m < 2; m++)
#pragma unroll
      for (int r = 0; r < 16; r++) {
        float a = (m == 0 ? acc0[r] : acc1[r]) + bb1;
        float e = __expf(a);
        float h = a > 0.f ? a : (e - 1.f);
        unsigned dd = f2bf(a > 0.f ? 1.f : e);
        storeWide(bufA, m, r, h);
        int idx = m * 8 + (r >> 1);
        d1p[idx] = (r & 1) ? (d1p[idx] | (dd << 16)) : dd;
      }
  }
  __syncthreads();

  // ---------------- G2: a2 = h1 @ W2^T + b2 ----------------
  {
    f32x16 acc0 = {}, acc1 = {};
#pragma unroll
    for (int s = 0; s < 16; s++) {
      bf16x8 a0 = wideA(bufA, 0, s);
      bf16x8 a1 = wideA(bufA, 1, s);
      bf16x8 B = Q2[(ns * 16 + s) * 64 + lane];
      acc0 = MFMA32(a0, B, acc0);
      acc1 = MFMA32(a1, B, acc1);
    }
#pragma unroll
    for (int m = 0; m < 2; m++)
#pragma unroll
      for (int r = 0; r < 16; r++) {
        float a = (m == 0 ? acc0[r] : acc1[r]) + bb2;
        float e = __expf(a);
        float h = a > 0.f ? a : (e - 1.f);
        unsigned dd = f2bf(a > 0.f ? 1.f : e);
        storeWide(bufB, m, r, h);
        int idx = m * 8 + (r >> 1);
        d2p[idx] = (r & 1) ? (d2p[idx] | (dd << 16)) : dd;
      }
  }
  __syncthreads();

  // ---------------- G3: z = y + h2 @ W3^T + b3 ; d0, v0 ----------------
  {
    f32x4 acc[2] = {};
#pragma unroll
    for (int s = 0; s < 8; s++) {
      bf16x8 B = Q3[(nt * 8 + s) * 64 + lane];
#pragma unroll
      for (int m = 0; m < 2; m++)
        acc[m] = MFMA16(narrA(bufB, m, s), B, acc[m]);
    }
#pragma unroll
    for (int m = 0; m < 2; m++)
#pragma unroll
      for (int r = 0; r < 4; r++) {
        int row = r0 + (mh * 2 + m) * 16 + g16 * 4 + r;
        int col = nt * 16 + l15;
        size_t off = (size_t)row * 64 + col;
        float yv = __builtin_nontemporal_load(y + off);
        __builtin_nontemporal_store(yv + acc[m][r] + bb3, out + off);
        unsigned dd = f2bf(yv > 0.f ? 1.f : __expf(yv));
        unsigned vv = f2bf(__builtin_nontemporal_load(v + off));
        int idx = m * 2 + (r >> 1);
        d0p[idx] = (r & 1) ? (d0p[idx] | (dd << 16)) : dd;
        v0p[idx] = (r & 1) ? (v0p[idx] | (vv << 16)) : vv;
      }
  }

  // ---------------- G4 (k=1): u2 = (v0 @ W3) * d2 ----------------
  {
    f32x16 acc0 = {}, acc1 = {};
#pragma unroll
    for (int s = 0; s < 4; s++) {
      bf16x8 a0, a1;
#pragma unroll
      for (int m = 0; m < 2; m++) {
        const float* vp = v + (size_t)(r0 + m * 32 + l31) * 64 + s * 16 + h32 * 8;
        f32x4 p = __builtin_nontemporal_load((const f32x4*)vp);
        f32x4 q = __builtin_nontemporal_load((const f32x4*)(vp + 4));
        float xv[8] = {p[0], p[1], p[2], p[3], q[0], q[1], q[2], q[3]};
        bf16x8 f;
#pragma unroll
        for (int i = 0; i < 8; i++) f[i] = (short)f2bf(xv[i]);
        if (m == 0) a0 = f; else a1 = f;
      }
      bf16x8 B = Q4[(ns * 4 + s) * 64 + lane];
      acc0 = MFMA32(a0, B, acc0);
      acc1 = MFMA32(a1, B, acc1);
    }
#pragma unroll
    for (int m = 0; m < 2; m++)
#pragma unroll
      for (int r = 0; r < 16; r++) {
        float u = (m == 0 ? acc0[r] : acc1[r]) * bf2f((d2p[m * 8 + (r >> 1)] >> ((r & 1) * 16)) & 0xffffu);
        storeWide(bufA, m, r, u);
      }
  }
  __syncthreads();

  // ---------------- backward iterations ----------------
  for (int k = 1; k <= 8; ++k) {
    // G5: u1 = (u2 @ W2) * d1
    {
      f32x16 acc0 = {}, acc1 = {};
#pragma unroll
      for (int s = 0; s < 16; s++) {
        bf16x8 a0 = wideA(bufA, 0, s);
        bf16x8 a1 = wideA(bufA, 1, s);
        bf16x8 B = Q5[(ns * 16 + s) * 64 + lane];
        acc0 = MFMA32(a0, B, acc0);
        acc1 = MFMA32(a1, B, acc1);
      }
#pragma unroll
      for (int m = 0; m < 2; m++)
#pragma unroll
        for (int r = 0; r < 16; r++) {
          float u = (m == 0 ? acc0[r] : acc1[r]) * bf2f((d1p[m * 8 + (r >> 1)] >> ((r & 1) * 16)) & 0xffffu);
          storeWide(bufB, m, r, u);
        }
    }
    __syncthreads();

    // G6: w' = (u1 @ W1) * d0 ; log-det ; w' -> wbuf
    {
      float coef = (k & 1) ? (1.f / (float)k) : (-1.f / (float)k);
      f32x4 acc[2] = {};
#pragma unroll
      for (int s = 0; s < 8; s++) {
        bf16x8 B = Q6[(nt * 8 + s) * 64 + lane];
#pragma unroll
        for (int m = 0; m < 2; m++)
          acc[m] = MFMA16(narrA(bufB, m, s), B, acc[m]);
      }
#pragma unroll
      for (int m = 0; m < 2; m++)
#pragma unroll
        for (int r = 0; r < 4; r++) {
          float wv = acc[m][r] * bf2f((d0p[m * 2 + (r >> 1)] >> ((r & 1) * 16)) & 0xffffu);
          ldacc[m * 4 + r] += coef * wv * bf2f((v0p[m * 2 + (r >> 1)] >> ((r & 1) * 16)) & 0xffffu);
          if (k < 8) {
            int row = (mh * 2 + m) * 16 + g16 * 4 + r;
            int col = nt * 16 + l15;
            *(unsigned short*)(wbuf + row * 128 + (((unsigned)(col * 2)) ^ ((unsigned)(row & 7) << 4))) = f2bf(wv);
          }
        }
    }
    if (k < 8) {
      __syncthreads();
      // G4': u2 = (w' @ W3) * d2
      f32x16 acc0 = {}, acc1 = {};
#pragma unroll
      for (int s = 0; s < 4; s++) {
        bf16x8 a0, a1;
#pragma unroll
        for (int m = 0; m < 2; m++) {
          int row = m * 32 + l31;
          unsigned byte = ((unsigned)(s * 32 + h32 * 16)) ^ ((unsigned)(row & 7) << 4);
          bf16x8 a = *(const bf16x8*)(wbuf + row * 128 + byte);
          if (m == 0) a0 = a; else a1 = a;
        }
        bf16x8 B = Q4[(ns * 4 + s) * 64 + lane];
        acc0 = MFMA32(a0, B, acc0);
        acc1 = MFMA32(a1, B, acc1);
      }
#pragma unroll
      for (int m = 0; m < 2; m++)
#pragma unroll
        for (int r = 0; r < 16; r++) {
          float u = (m == 0 ? acc0[r] : acc1[r]) * bf2f((d2p[m * 8 + (r >> 1)] >> ((r & 1) * 16)) & 0xffffu);
          storeWide(bufA, m, r, u);
        }
      __syncthreads();
    }
  }

  // ---------------- log-det epilogue ----------------
#pragma unroll
  for (int i = 0; i < 8; i++) {
    float s = ldacc[i];
    s += __shfl_xor(s, 1);
    s += __shfl_xor(s, 2);
    s += __shfl_xor(s, 4);
    s += __shfl_xor(s, 8);
    ldacc[i] = s;
  }
  if (l15 == 0) {
#pragma unroll
    for (int m = 0; m < 2; m++)
#pragma unroll
      for (int r = 0; r < 4; r++) {
        int row = (mh * 2 + m) * 16 + g16 * 4 + r;
        ldp[row * 4 + nt] = ldacc[m * 4 + r];
      }
  }
  __syncthreads();
  if (tid < 64) {
    float s = ldp[tid * 4] + ldp[tid * 4 + 1] + ldp[tid * 4 + 2] + ldp[tid * 4 + 3];
    int gb = r0 + tid;
    __builtin_nontemporal_store(ldj[gb] + s, out + (size_t)BN * 64 + gb);
  }
}

extern "C" void kernel_launch(void* const* d_in, const int* in_sizes, int n_in,
                              void* d_out, int out_size, void* d_ws, size_t ws_size,
                              hipStream_t stream) {
  const float* y   = (const float*)d_in[0];
  const float* ldj = (const float*)d_in[1];
  const float* v   = (const float*)d_in[2];
  const float* W1  = (const float*)d_in[3];
  const float* b1  = (const float*)d_in[4];
  const float* W2  = (const float*)d_in[5];
  const float* b2  = (const float*)d_in[6];
  const float* W3  = (const float*)d_in[7];
  const float* b3  = (const float*)d_in[8];
  unsigned short* wsb = (unsigned short*)d_ws;
  float* out = (float*)d_out;

  (void)hipFuncSetAttribute(reinterpret_cast<const void*>(&invres_main),
                            hipFuncAttributeMaxDynamicSharedMemorySize, L_SIZE);

  invres_prep<<<N_WS / 256, 256, 0, stream>>>(W1, W2, W3, wsb);
  invres_main<<<BN / 64, 512, L_SIZE, stream>>>(y, ldj, v, b1, b2, b3, wsb, out);
}